// Round 7
// baseline (437.693 us; speedup 1.0000x reference)
//
#include <hip/hip_runtime.h>
#include <hip/hip_bf16.h>

// B=2, H=16, L=2048, D=64. BH=32 flattened heads.
// MFMA flash attention, round 7 = round 6 + serial-chain cuts:
//  - exp2-domain softmax: Q pre-scaled by 0.125*log2(e); exp = bare v_exp_f32.
//  - T13 defer-max (THR=8 in log2 units): skip acc-rescale + alpha-shuffles
//    when __all(vm <= mr+8) — the common case; p bounded by 2^8, f32-safe.
//  - V ds_reads hoisted above the score MFMAs (LDS latency under MFMA+VALU).
//  - s_setprio(1) around the two MFMA clusters (T5).
// Carried from round 6: swapped QK^T (scalar per-lane softmax stats),
// in-register P redistribution (16 bpermute), K/E/V double-buffer with one
// barrier per trip, paired q-tiles (waves 0-3: qa, 4-7: 31-qa) + rotation,
// staging role split, swizzled LDS layouts, split-precision 3-MFMA scheme.
// Runtime dtype detection kept (flag in d_ws); both instantiations launch,
// wrong one early-exits. mask input (d_in[5]) is pure causal -> analytic.

typedef unsigned short u16;
typedef unsigned int   u32;
typedef __attribute__((ext_vector_type(8))) short bf16x8;  // 8 bf16 (4 VGPR)
typedef __attribute__((ext_vector_type(4))) float f32x4;   // MFMA acc

#define L_SEQ 2048
#define D_DIM 64
#define BQ    64            // q rows per tile = 4 waves x 16
#define BK    32            // keys per tile
#define NQT   (L_SEQ / BQ)  // 32 q-tiles per head

__device__ __forceinline__ float bf2f(u32 lo16) {
    u32 u = lo16 << 16; float f; __builtin_memcpy(&f, &u, 4); return f;
}

__global__ void detect_dtype_kernel(const u16* __restrict__ q, int* __restrict__ flag) {
    const int lane = threadIdx.x;             // 64 threads, 1 block
    float x = fabsf(bf2f((u32)q[lane]));
    bool big = !(x <= 100.f);                 // fp32 mantissa bits look like wild bf16
    unsigned long long m = __ballot(big);
    if (lane == 0) *flag = (m != 0ull) ? 1 : 0;  // 1 = fp32, 0 = bf16
}

// ---- truncating hi/lo split of 8 f32 -> packed bf16 uint4 pair ----
__device__ __forceinline__ void split_pack(const float* x, uint4& h, uint4& l) {
    u32 xb[8], rb[8];
#pragma unroll
    for (int j = 0; j < 8; ++j) {
        __builtin_memcpy(&xb[j], &x[j], 4);
        u32 hb = xb[j] & 0xffff0000u;
        float hf; __builtin_memcpy(&hf, &hb, 4);
        float r = x[j] - hf;                  // exact residual of truncation
        __builtin_memcpy(&rb[j], &r, 4);
    }
    h.x = (xb[0] >> 16) | (xb[1] & 0xffff0000u);
    h.y = (xb[2] >> 16) | (xb[3] & 0xffff0000u);
    h.z = (xb[4] >> 16) | (xb[5] & 0xffff0000u);
    h.w = (xb[6] >> 16) | (xb[7] & 0xffff0000u);
    l.x = (rb[0] >> 16) | (rb[1] & 0xffff0000u);
    l.y = (rb[2] >> 16) | (rb[3] & 0xffff0000u);
    l.z = (rb[4] >> 16) | (rb[5] & 0xffff0000u);
    l.w = (rb[6] >> 16) | (rb[7] & 0xffff0000u);
}

template<bool IS_F32>
__device__ __forceinline__ void unpack8(const uint4& a, const uint4& b, float* x) {
    if (IS_F32) {
        u32 w[8] = {a.x, a.y, a.z, a.w, b.x, b.y, b.z, b.w};
#pragma unroll
        for (int j = 0; j < 8; ++j) __builtin_memcpy(&x[j], &w[j], 4);
    } else {
        u32 w[4] = {a.x, a.y, a.z, a.w};
#pragma unroll
        for (int j = 0; j < 4; ++j) {
            x[2*j]   = bf2f(w[j] & 0xffffu);
            x[2*j+1] = bf2f(w[j] >> 16);
        }
    }
}

struct StKE { uint4 k0, k1, e0, e1; };   // bf16 path uses k0/e0 only
struct StV  { u32 v[8]; };

template<bool IS_F32>
__device__ __forceinline__ void issue_ke(const void* Kv, const void* Ev,
        size_t base, int kbase, int r, int j8, StKE& R) {
    const size_t off = base + (size_t)(kbase + r) * D_DIM + j8 * 8;
    if (IS_F32) {
        const uint4* kp = (const uint4*)((const float*)Kv + off);
        R.k0 = kp[0]; R.k1 = kp[1];
        const uint4* ep = (const uint4*)((const float*)Ev + off);
        R.e0 = ep[0]; R.e1 = ep[1];
    } else {
        R.k0 = *(const uint4*)((const u16*)Kv + off);
        R.e0 = *(const uint4*)((const u16*)Ev + off);
    }
}

template<bool IS_F32>
__device__ __forceinline__ void issue_v(const void* Vv,
        size_t base, int kbase, int d, int kg, StV& R) {
    const size_t off = base + (size_t)(kbase + kg * 8) * D_DIM + d;
    if (IS_F32) {
        const u32* vp = (const u32*)((const float*)Vv + off);
#pragma unroll
        for (int j = 0; j < 8; ++j) R.v[j] = vp[j * D_DIM];   // one dim, 8 keys
    } else {
        const u16* vp = (const u16*)Vv + off;
#pragma unroll
        for (int j = 0; j < 8; ++j) R.v[j] = (u32)vp[j * D_DIM];
    }
}

#define MFMA(a, b, c) __builtin_amdgcn_mfma_f32_16x16x32_bf16((a), (b), (c), 0, 0, 0)

template<bool IS_F32>
__global__ __launch_bounds__(512, 4) void attn_pair(
    const void* __restrict__ Qv, const void* __restrict__ Kv,
    const void* __restrict__ Vv, const void* __restrict__ PQv,
    const void* __restrict__ PKv, void* __restrict__ Ov,
    const int* __restrict__ flag)
{
    if (((*flag) != 0) != IS_F32) return;    // wrong dtype for this instantiation

    const int bh   = blockIdx.y;
    const int qa   = ((int)blockIdx.x + bh) & 15;   // rotation balances CUs
    const int t    = threadIdx.x;
    const int w    = t >> 6;                 // wave 0..7
    const int lane = t & 63;
    const int g    = lane >> 4;              // 16-lane group 0..3
    const int c    = lane & 15;
    const size_t base = (size_t)bh * L_SEQ * D_DIM;
    const int qtile = (w < 4) ? qa : (31 - qa);     // light / heavy q-tile
    const int qb_w  = qtile * BQ + (w & 3) * 16;    // this wave's first q row
    const int nkt   = 64 - 2 * qa;           // heavy tile's k-tile count (covers light)

    // LDS: double-buffered swizzled tile images (rows 256B, 16B slots XOR'd).
    __shared__ __align__(16) u16 Kt[2][BK * 128];     // 16 KB
    __shared__ __align__(16) u16 Et[2][BK * 128];     // 16 KB
    __shared__ __align__(16) u16 Vt[2][32 * 128];     // 16 KB
    // total 48 KB -> 2 blocks/CU (grid is 2/CU anyway)

    // ---- Q & PE_Q fragments, pre-scaled by 0.125*log2(e) (exp2 domain) ----
    // Split-pack is AFTER scaling, so the hi/lo pair is exact regardless.
    bf16x8 qa_h[4], qa_l[4];                 // ch 0,1 = Q d0=0,32 ; ch 2,3 = PE_Q
    {
        const int qrow = qb_w + c;
#pragma unroll
        for (int ch = 0; ch < 4; ++ch) {
            const void* src = (ch < 2) ? Qv : PQv;
            const int d0 = (ch & 1) * 32 + 8 * g;
            const size_t off = base + (size_t)qrow * D_DIM + d0;
            float x[8];
            if (IS_F32) {
                const uint4* gp = (const uint4*)((const float*)src + off);
                unpack8<true>(gp[0], gp[1], x);
            } else {
                uint4 a = *(const uint4*)((const u16*)src + off);
                unpack8<false>(a, a, x);
            }
#pragma unroll
            for (int j = 0; j < 8; ++j) x[j] *= 0.1803368801f;  // (1/8)*log2(e)
            uint4 hp, lp; split_pack(x, hp, lp);
            u32 hw[4] = {hp.x, hp.y, hp.z, hp.w}, lw[4] = {lp.x, lp.y, lp.z, lp.w};
#pragma unroll
            for (int j = 0; j < 4; ++j) {
                qa_h[ch][2*j]   = (short)(hw[j] & 0xffffu);
                qa_h[ch][2*j+1] = (short)(hw[j] >> 16);
                qa_l[ch][2*j]   = (short)(lw[j] & 0xffffu);
                qa_l[ch][2*j+1] = (short)(lw[j] >> 16);
            }
        }
    }

    float mr = -INFINITY, lr = 0.f;          // scalar stats (log2 domain max)
    f32x4 acc[4];
#pragma unroll
    for (int df = 0; df < 4; ++df) acc[df] = (f32x4){0.f, 0.f, 0.f, 0.f};

    // ---- staging roles: waves 0-3 stage K+PE, waves 4-7 stage V ----
    const bool is_ke = (t < 256);
    const int ts   = t & 255;
    const int r_t  = ts >> 3;                // K/E: row (key) 0..31
    const int j8_t = ts & 7;                 // K/E: 8-elem chunk 0..7
    const int d_t  = ts & 63;                // V: dim 0..63
    const int kg_t = (ts >> 6) & 3;          // V: key chunk 0..3
    const int ke_wo = r_t * 128 + (j8_t ^ (r_t & 7)) * 8;           // hi; lo at +64
    const int v_rr  = d_t >> 1;
    const int v_wo  = v_rr * 128 + ((4 * (d_t & 1) + kg_t) ^ (v_rr & 7)) * 8;

    StKE Rke; StV Rv;

    auto stage_store = [&](int b) {
        if (is_ke) {
            float x[8]; uint4 hp, lp;
            unpack8<IS_F32>(Rke.k0, Rke.k1, x);
            split_pack(x, hp, lp);
            *(uint4*)(&Kt[b][0] + ke_wo)      = hp;
            *(uint4*)(&Kt[b][0] + ke_wo + 64) = lp;
            unpack8<IS_F32>(Rke.e0, Rke.e1, x);
            split_pack(x, hp, lp);
            *(uint4*)(&Et[b][0] + ke_wo)      = hp;
            *(uint4*)(&Et[b][0] + ke_wo + 64) = lp;
        } else {
            float x[8]; uint4 hp, lp;
#pragma unroll
            for (int j = 0; j < 8; ++j) {
                if (IS_F32) __builtin_memcpy(&x[j], &Rv.v[j], 4);
                else        x[j] = bf2f(Rv.v[j]);
            }
            split_pack(x, hp, lp);
            *(uint4*)(&Vt[b][0] + v_wo)      = hp;
            *(uint4*)(&Vt[b][0] + v_wo + 64) = lp;
        }
    };
    auto issue = [&](int kbase) {
        if (is_ke) issue_ke<IS_F32>(Kv, PKv, base, kbase, r_t, j8_t, Rke);
        else       issue_v <IS_F32>(Vv, base, kbase, d_t, kg_t, Rv);
    };

    // ---- prologue: tile 0 into buf 0; tile 1 in flight ----
    issue(0);
    stage_store(0);
    issue(BK);
    __syncthreads();

    const int c7 = c & 7;
    const int srcA = 32 * (g & 1) + c;       // P-shuffle sources (own column)
    const int srcB = srcA + 16;
    const int sv = ((4 * (c & 1) + g) ^ ((c >> 1) & 7)) * 8;  // V/P slot formula

    for (int kt = 0; kt < nkt; ++kt) {
        const int cur = kt & 1;
        const int kbase = kt * BK;

        if (kt + 1 < nkt) {                  // stage next tile into other buffer
            stage_store(cur ^ 1);
            if (kt + 2 < nkt) issue(kbase + 2 * BK);
        }

        if (kbase <= qb_w + 15) {            // wave-uniform: tile has unmasked keys
            const bool do1 = (kbase + 16 <= qb_w + 15);
            const u16* Ktc = &Kt[cur][0];
            const u16* Etc = &Et[cur][0];
            const u16* Vtc = &Vt[cur][0];
            // ---- hoisted V reads: latency hides under scores + softmax ----
            bf16x8 vbh[4], vbl[4];
#pragma unroll
            for (int df = 0; df < 4; ++df) {
                const u16* vw = Vtc + (8 * df + (c >> 1)) * 128;
                vbh[df] = *(const bf16x8*)(vw + sv);
                vbl[df] = *(const bf16x8*)(vw + sv + 64);
            }
            // ---- scores: S^T = K.Q^T (+ PEk.PEq^T), split precision ----
            // Lane (g,c): s0[i] = S[key kbase+4g+i][query qb_w+c], s1: key+16.
            f32x4 s0 = {0,0,0,0}, s1 = {0,0,0,0};
            __builtin_amdgcn_s_setprio(1);
#pragma unroll
            for (int ch = 0; ch < 4; ++ch) {
                const u16* Bp = (ch < 2) ? Ktc : Etc;
                const int sh = ((((ch & 1) * 4 + g) ^ c7)) * 8;
                const u16* r0 = Bp + c * 128;
                bf16x8 b0h = *(const bf16x8*)(r0 + sh);
                bf16x8 b0l = *(const bf16x8*)(r0 + sh + 64);
                s0 = MFMA(b0h, qa_h[ch], s0);    // Kh.Qh
                s0 = MFMA(b0l, qa_h[ch], s0);    // Kl.Qh
                s0 = MFMA(b0h, qa_l[ch], s0);    // Kh.Ql
                if (do1) {
                    const u16* r1 = Bp + (c + 16) * 128;   // (c+16)&7 == c&7
                    bf16x8 b1h = *(const bf16x8*)(r1 + sh);
                    bf16x8 b1l = *(const bf16x8*)(r1 + sh + 64);
                    s1 = MFMA(b1h, qa_h[ch], s1);
                    s1 = MFMA(b1l, qa_h[ch], s1);
                    s1 = MFMA(b1h, qa_l[ch], s1);
                }
            }
            __builtin_amdgcn_s_setprio(0);
            // ---- causal mask (rows = keys now): key > query -> -inf ----
            const int qrow = qb_w + c;
#pragma unroll
            for (int i = 0; i < 4; ++i) {
                if (kbase + 4 * g + i > qrow)                s0[i] = -INFINITY;
                if (!do1 || kbase + 16 + 4 * g + i > qrow)   s1[i] = -INFINITY;
            }
            // ---- per-query (per-lane) softmax in exp2 domain, defer-max ----
            float vm = fmaxf(fmaxf(fmaxf(s0[0], s0[1]), fmaxf(s0[2], s0[3])),
                             fmaxf(fmaxf(s1[0], s1[1]), fmaxf(s1[2], s1[3])));
            vm = fmaxf(vm, __shfl_xor(vm, 16));
            vm = fmaxf(vm, __shfl_xor(vm, 32));
            if (!__all(vm <= mr + 8.f)) {        // rescale needed (rare later)
                const float mn = fmaxf(mr, vm);
                const float al = exp2f(mr - mn); // exp2(-inf)=0 on first tile
                mr = mn;
                lr *= al;
                float al4[4];
#pragma unroll
                for (int i = 0; i < 4; ++i) al4[i] = __shfl(al, 20 * g + i);
#pragma unroll
                for (int df = 0; df < 4; ++df) {
#pragma unroll
                    for (int i = 0; i < 4; ++i) acc[df][i] *= al4[i];
                }
            }
            float p0f[4], p1f[4];
#pragma unroll
            for (int i = 0; i < 4; ++i) {
                p0f[i] = exp2f(s0[i] - mr);      // masked -> exp2(-inf)=0
                p1f[i] = exp2f(s1[i] - mr);      // bounded by 2^8 when deferred
            }
            float rs = (p0f[0] + p0f[1]) + (p0f[2] + p0f[3])
                     + (p1f[0] + p1f[1]) + (p1f[2] + p1f[3]);
            rs += __shfl_xor(rs, 16);
            rs += __shfl_xor(rs, 32);
            lr += rs;
            // ---- P -> PV A-fragment, fully in-register ----
            u32 w0[4], w1[4];
#pragma unroll
            for (int i = 0; i < 4; ++i) {
                const float x0 = p0f[i];
                u32 b0; __builtin_memcpy(&b0, &x0, 4);
                u32 h0 = b0 & 0xffff0000u; float h0f; __builtin_memcpy(&h0f, &h0, 4);
                float l0f = x0 - h0f; u32 l0; __builtin_memcpy(&l0, &l0f, 4);
                w0[i] = (b0 >> 16) | (l0 & 0xffff0000u);
                const float x1 = p1f[i];
                u32 b1; __builtin_memcpy(&b1, &x1, 4);
                u32 h1 = b1 & 0xffff0000u; float h1f; __builtin_memcpy(&h1f, &h1, 4);
                float l1f = x1 - h1f; u32 l1; __builtin_memcpy(&l1, &l1f, 4);
                w1[i] = (b1 >> 16) | (l1 & 0xffff0000u);
            }
            const bool lowhalf = (lane < 32);    // g<2 -> keys<16 -> p0 array
            bf16x8 pa_h, pa_l;
#pragma unroll
            for (int i = 0; i < 4; ++i) {
                u32 t0a = (u32)__shfl((int)w0[i], srcA);
                u32 t1a = (u32)__shfl((int)w1[i], srcA);
                u32 t0b = (u32)__shfl((int)w0[i], srcB);
                u32 t1b = (u32)__shfl((int)w1[i], srcB);
                u32 ha = lowhalf ? t0a : t1a;
                u32 hb = lowhalf ? t0b : t1b;
                pa_h[i]     = (short)(ha & 0xffffu);
                pa_h[4 + i] = (short)(hb & 0xffffu);
                pa_l[i]     = (short)(ha >> 16);
                pa_l[4 + i] = (short)(hb >> 16);
            }
            // ---- PV: acc += P.V (split precision: PhVh + PhVl + PlVh) ----
            __builtin_amdgcn_s_setprio(1);
#pragma unroll
            for (int df = 0; df < 4; ++df) {
                acc[df] = MFMA(pa_h, vbh[df], acc[df]);
                acc[df] = MFMA(pa_h, vbl[df], acc[df]);
                acc[df] = MFMA(pa_l, vbh[df], acc[df]);
            }
            __builtin_amdgcn_s_setprio(0);
        }
        __syncthreads();                     // end of trip: buf^1 now complete
    }

    // ---- epilogue: 1/l for query 4g+i lives at lane 20g+i ----
    float inv[4];
#pragma unroll
    for (int i = 0; i < 4; ++i) inv[i] = 1.f / __shfl(lr, 20 * g + i);
    if (IS_F32) {
        float* o = (float*)Ov + base;
#pragma unroll
        for (int df = 0; df < 4; ++df)
#pragma unroll
            for (int i = 0; i < 4; ++i)
                o[(size_t)(qb_w + 4 * g + i) * D_DIM + 16 * df + c] = acc[df][i] * inv[i];
    } else {
        __hip_bfloat16* o = (__hip_bfloat16*)Ov + base;
#pragma unroll
        for (int df = 0; df < 4; ++df)
#pragma unroll
            for (int i = 0; i < 4; ++i)
                o[(size_t)(qb_w + 4 * g + i) * D_DIM + 16 * df + c] =
                    __float2bfloat16(acc[df][i] * inv[i]);
    }
}

extern "C" void kernel_launch(void* const* d_in, const int* in_sizes, int n_in,
                              void* d_out, int out_size, void* d_ws, size_t ws_size,
                              hipStream_t stream) {
    const void* q  = d_in[0];
    const void* k  = d_in[1];
    const void* v  = d_in[2];
    const void* pq = d_in[3];
    const void* pk = d_in[4];
    // d_in[5] = causal mask, recomputed analytically in-kernel.
    int* flag = (int*)d_ws;

    detect_dtype_kernel<<<1, 64, 0, stream>>>((const u16*)q, flag);

    dim3 grid(NQT / 2, 32);                  // 16 pairs x 32 heads = 512 blocks
    attn_pair<false><<<grid, 512, 0, stream>>>(q, k, v, pq, pk, d_out, flag);
    attn_pair<true ><<<grid, 512, 0, stream>>>(q, k, v, pq, pk, d_out, flag);
}

// Round 8
// 254.753 us; speedup vs baseline: 1.7181x; 1.7181x over previous
//
#include <hip/hip_runtime.h>
#include <hip/hip_bf16.h>

// B=2, H=16, L=2048, D=64. BH=32 flattened heads.
// MFMA flash attention, round 8 = round 6 structure (proven 167us hot)
// + pressure-neutral cuts only:
//  - exp2-domain softmax: Q pre-scaled by 0.125*log2(e); bare v_exp_f32.
//  - T13 defer-max (THR=8 log2): skip acc-rescale + alpha-shuffles when
//    __all(vm <= mr+8); p bounded by 2^8, f32-safe. Wave-uniform branch.
//  - s_setprio(1) around the two MFMA clusters (T5).
//  - NO V-read hoist (round 7's +32 live VGPRs caused scratch spills:
//    WRITE_SIZE 20->67MB, 2x regression). V reads stay inside the PV loop.
// Carried from round 6: swapped QK^T (per-lane scalar softmax stats),
// in-register P redistribution (16 bpermute), K/E/V double-buffer with one
// barrier per trip, paired q-tiles (waves 0-3: qa, 4-7: 31-qa) + rotation,
// staging role split, swizzled LDS layouts, split-precision 3-MFMA scheme.
// Runtime dtype detection kept (flag in d_ws); both instantiations launch,
// wrong one early-exits. mask input (d_in[5]) is pure causal -> analytic.

typedef unsigned short u16;
typedef unsigned int   u32;
typedef __attribute__((ext_vector_type(8))) short bf16x8;  // 8 bf16 (4 VGPR)
typedef __attribute__((ext_vector_type(4))) float f32x4;   // MFMA acc

#define L_SEQ 2048
#define D_DIM 64
#define BQ    64            // q rows per tile = 4 waves x 16
#define BK    32            // keys per tile
#define NQT   (L_SEQ / BQ)  // 32 q-tiles per head

__device__ __forceinline__ float bf2f(u32 lo16) {
    u32 u = lo16 << 16; float f; __builtin_memcpy(&f, &u, 4); return f;
}

__global__ void detect_dtype_kernel(const u16* __restrict__ q, int* __restrict__ flag) {
    const int lane = threadIdx.x;             // 64 threads, 1 block
    float x = fabsf(bf2f((u32)q[lane]));
    bool big = !(x <= 100.f);                 // fp32 mantissa bits look like wild bf16
    unsigned long long m = __ballot(big);
    if (lane == 0) *flag = (m != 0ull) ? 1 : 0;  // 1 = fp32, 0 = bf16
}

// ---- truncating hi/lo split of 8 f32 -> packed bf16 uint4 pair ----
__device__ __forceinline__ void split_pack(const float* x, uint4& h, uint4& l) {
    u32 xb[8], rb[8];
#pragma unroll
    for (int j = 0; j < 8; ++j) {
        __builtin_memcpy(&xb[j], &x[j], 4);
        u32 hb = xb[j] & 0xffff0000u;
        float hf; __builtin_memcpy(&hf, &hb, 4);
        float r = x[j] - hf;                  // exact residual of truncation
        __builtin_memcpy(&rb[j], &r, 4);
    }
    h.x = (xb[0] >> 16) | (xb[1] & 0xffff0000u);
    h.y = (xb[2] >> 16) | (xb[3] & 0xffff0000u);
    h.z = (xb[4] >> 16) | (xb[5] & 0xffff0000u);
    h.w = (xb[6] >> 16) | (xb[7] & 0xffff0000u);
    l.x = (rb[0] >> 16) | (rb[1] & 0xffff0000u);
    l.y = (rb[2] >> 16) | (rb[3] & 0xffff0000u);
    l.z = (rb[4] >> 16) | (rb[5] & 0xffff0000u);
    l.w = (rb[6] >> 16) | (rb[7] & 0xffff0000u);
}

template<bool IS_F32>
__device__ __forceinline__ void unpack8(const uint4& a, const uint4& b, float* x) {
    if (IS_F32) {
        u32 w[8] = {a.x, a.y, a.z, a.w, b.x, b.y, b.z, b.w};
#pragma unroll
        for (int j = 0; j < 8; ++j) __builtin_memcpy(&x[j], &w[j], 4);
    } else {
        u32 w[4] = {a.x, a.y, a.z, a.w};
#pragma unroll
        for (int j = 0; j < 4; ++j) {
            x[2*j]   = bf2f(w[j] & 0xffffu);
            x[2*j+1] = bf2f(w[j] >> 16);
        }
    }
}

struct StKE { uint4 k0, k1, e0, e1; };   // bf16 path uses k0/e0 only
struct StV  { u32 v[8]; };

template<bool IS_F32>
__device__ __forceinline__ void issue_ke(const void* Kv, const void* Ev,
        size_t base, int kbase, int r, int j8, StKE& R) {
    const size_t off = base + (size_t)(kbase + r) * D_DIM + j8 * 8;
    if (IS_F32) {
        const uint4* kp = (const uint4*)((const float*)Kv + off);
        R.k0 = kp[0]; R.k1 = kp[1];
        const uint4* ep = (const uint4*)((const float*)Ev + off);
        R.e0 = ep[0]; R.e1 = ep[1];
    } else {
        R.k0 = *(const uint4*)((const u16*)Kv + off);
        R.e0 = *(const uint4*)((const u16*)Ev + off);
    }
}

template<bool IS_F32>
__device__ __forceinline__ void issue_v(const void* Vv,
        size_t base, int kbase, int d, int kg, StV& R) {
    const size_t off = base + (size_t)(kbase + kg * 8) * D_DIM + d;
    if (IS_F32) {
        const u32* vp = (const u32*)((const float*)Vv + off);
#pragma unroll
        for (int j = 0; j < 8; ++j) R.v[j] = vp[j * D_DIM];   // one dim, 8 keys
    } else {
        const u16* vp = (const u16*)Vv + off;
#pragma unroll
        for (int j = 0; j < 8; ++j) R.v[j] = (u32)vp[j * D_DIM];
    }
}

#define MFMA(a, b, c) __builtin_amdgcn_mfma_f32_16x16x32_bf16((a), (b), (c), 0, 0, 0)

template<bool IS_F32>
__global__ __launch_bounds__(512, 4) void attn_pair(
    const void* __restrict__ Qv, const void* __restrict__ Kv,
    const void* __restrict__ Vv, const void* __restrict__ PQv,
    const void* __restrict__ PKv, void* __restrict__ Ov,
    const int* __restrict__ flag)
{
    if (((*flag) != 0) != IS_F32) return;    // wrong dtype for this instantiation

    const int bh   = blockIdx.y;
    const int qa   = ((int)blockIdx.x + bh) & 15;   // rotation balances CUs
    const int t    = threadIdx.x;
    const int w    = t >> 6;                 // wave 0..7
    const int lane = t & 63;
    const int g    = lane >> 4;              // 16-lane group 0..3
    const int c    = lane & 15;
    const size_t base = (size_t)bh * L_SEQ * D_DIM;
    const int qtile = (w < 4) ? qa : (31 - qa);     // light / heavy q-tile
    const int qb_w  = qtile * BQ + (w & 3) * 16;    // this wave's first q row
    const int nkt   = 64 - 2 * qa;           // heavy tile's k-tile count (covers light)

    // LDS: double-buffered swizzled tile images (rows 256B, 16B slots XOR'd).
    __shared__ __align__(16) u16 Kt[2][BK * 128];     // 16 KB
    __shared__ __align__(16) u16 Et[2][BK * 128];     // 16 KB
    __shared__ __align__(16) u16 Vt[2][32 * 128];     // 16 KB
    // total 48 KB -> 2 blocks/CU (grid is 2/CU anyway)

    // ---- Q & PE_Q fragments, pre-scaled by 0.125*log2(e) (exp2 domain) ----
    // Split-pack is AFTER scaling, so the hi/lo pair is exact regardless.
    bf16x8 qa_h[4], qa_l[4];                 // ch 0,1 = Q d0=0,32 ; ch 2,3 = PE_Q
    {
        const int qrow = qb_w + c;
#pragma unroll
        for (int ch = 0; ch < 4; ++ch) {
            const void* src = (ch < 2) ? Qv : PQv;
            const int d0 = (ch & 1) * 32 + 8 * g;
            const size_t off = base + (size_t)qrow * D_DIM + d0;
            float x[8];
            if (IS_F32) {
                const uint4* gp = (const uint4*)((const float*)src + off);
                unpack8<true>(gp[0], gp[1], x);
            } else {
                uint4 a = *(const uint4*)((const u16*)src + off);
                unpack8<false>(a, a, x);
            }
#pragma unroll
            for (int j = 0; j < 8; ++j) x[j] *= 0.1803368801f;  // (1/8)*log2(e)
            uint4 hp, lp; split_pack(x, hp, lp);
            u32 hw[4] = {hp.x, hp.y, hp.z, hp.w}, lw[4] = {lp.x, lp.y, lp.z, lp.w};
#pragma unroll
            for (int j = 0; j < 4; ++j) {
                qa_h[ch][2*j]   = (short)(hw[j] & 0xffffu);
                qa_h[ch][2*j+1] = (short)(hw[j] >> 16);
                qa_l[ch][2*j]   = (short)(lw[j] & 0xffffu);
                qa_l[ch][2*j+1] = (short)(lw[j] >> 16);
            }
        }
    }

    float mr = -INFINITY, lr = 0.f;          // scalar stats (log2-domain max)
    f32x4 acc[4];
#pragma unroll
    for (int df = 0; df < 4; ++df) acc[df] = (f32x4){0.f, 0.f, 0.f, 0.f};

    // ---- staging roles: waves 0-3 stage K+PE, waves 4-7 stage V ----
    const bool is_ke = (t < 256);
    const int ts   = t & 255;
    const int r_t  = ts >> 3;                // K/E: row (key) 0..31
    const int j8_t = ts & 7;                 // K/E: 8-elem chunk 0..7
    const int d_t  = ts & 63;                // V: dim 0..63
    const int kg_t = (ts >> 6) & 3;          // V: key chunk 0..3
    const int ke_wo = r_t * 128 + (j8_t ^ (r_t & 7)) * 8;           // hi; lo at +64
    const int v_rr  = d_t >> 1;
    const int v_wo  = v_rr * 128 + ((4 * (d_t & 1) + kg_t) ^ (v_rr & 7)) * 8;

    StKE Rke; StV Rv;

    auto stage_store = [&](int b) {
        if (is_ke) {
            float x[8]; uint4 hp, lp;
            unpack8<IS_F32>(Rke.k0, Rke.k1, x);
            split_pack(x, hp, lp);
            *(uint4*)(&Kt[b][0] + ke_wo)      = hp;
            *(uint4*)(&Kt[b][0] + ke_wo + 64) = lp;
            unpack8<IS_F32>(Rke.e0, Rke.e1, x);
            split_pack(x, hp, lp);
            *(uint4*)(&Et[b][0] + ke_wo)      = hp;
            *(uint4*)(&Et[b][0] + ke_wo + 64) = lp;
        } else {
            float x[8]; uint4 hp, lp;
#pragma unroll
            for (int j = 0; j < 8; ++j) {
                if (IS_F32) __builtin_memcpy(&x[j], &Rv.v[j], 4);
                else        x[j] = bf2f(Rv.v[j]);
            }
            split_pack(x, hp, lp);
            *(uint4*)(&Vt[b][0] + v_wo)      = hp;
            *(uint4*)(&Vt[b][0] + v_wo + 64) = lp;
        }
    };
    auto issue = [&](int kbase) {
        if (is_ke) issue_ke<IS_F32>(Kv, PKv, base, kbase, r_t, j8_t, Rke);
        else       issue_v <IS_F32>(Vv, base, kbase, d_t, kg_t, Rv);
    };

    // ---- prologue: tile 0 into buf 0; tile 1 in flight ----
    issue(0);
    stage_store(0);
    issue(BK);
    __syncthreads();

    const int c7 = c & 7;
    const int srcA = 32 * (g & 1) + c;       // P-shuffle sources (own column)
    const int srcB = srcA + 16;
    const int sv = ((4 * (c & 1) + g) ^ ((c >> 1) & 7)) * 8;  // V/P slot formula

    for (int kt = 0; kt < nkt; ++kt) {
        const int cur = kt & 1;
        const int kbase = kt * BK;

        if (kt + 1 < nkt) {                  // stage next tile into other buffer
            stage_store(cur ^ 1);
            if (kt + 2 < nkt) issue(kbase + 2 * BK);
        }

        if (kbase <= qb_w + 15) {            // wave-uniform: tile has unmasked keys
            const bool do1 = (kbase + 16 <= qb_w + 15);
            const u16* Ktc = &Kt[cur][0];
            const u16* Etc = &Et[cur][0];
            const u16* Vtc = &Vt[cur][0];
            // ---- scores: S^T = K.Q^T (+ PEk.PEq^T), split precision ----
            // Lane (g,c): s0[i] = S[key kbase+4g+i][query qb_w+c], s1: key+16.
            f32x4 s0 = {0,0,0,0}, s1 = {0,0,0,0};
            __builtin_amdgcn_s_setprio(1);
#pragma unroll
            for (int ch = 0; ch < 4; ++ch) {
                const u16* Bp = (ch < 2) ? Ktc : Etc;
                const int sh = ((((ch & 1) * 4 + g) ^ c7)) * 8;
                const u16* r0 = Bp + c * 128;
                bf16x8 b0h = *(const bf16x8*)(r0 + sh);
                bf16x8 b0l = *(const bf16x8*)(r0 + sh + 64);
                s0 = MFMA(b0h, qa_h[ch], s0);    // Kh.Qh
                s0 = MFMA(b0l, qa_h[ch], s0);    // Kl.Qh
                s0 = MFMA(b0h, qa_l[ch], s0);    // Kh.Ql
                if (do1) {
                    const u16* r1 = Bp + (c + 16) * 128;   // (c+16)&7 == c&7
                    bf16x8 b1h = *(const bf16x8*)(r1 + sh);
                    bf16x8 b1l = *(const bf16x8*)(r1 + sh + 64);
                    s1 = MFMA(b1h, qa_h[ch], s1);
                    s1 = MFMA(b1l, qa_h[ch], s1);
                    s1 = MFMA(b1h, qa_l[ch], s1);
                }
            }
            __builtin_amdgcn_s_setprio(0);
            // ---- causal mask (rows = keys now): key > query -> -inf ----
            const int qrow = qb_w + c;
#pragma unroll
            for (int i = 0; i < 4; ++i) {
                if (kbase + 4 * g + i > qrow)                s0[i] = -INFINITY;
                if (!do1 || kbase + 16 + 4 * g + i > qrow)   s1[i] = -INFINITY;
            }
            // ---- per-query (per-lane) softmax in exp2 domain, defer-max ----
            float vm = fmaxf(fmaxf(fmaxf(s0[0], s0[1]), fmaxf(s0[2], s0[3])),
                             fmaxf(fmaxf(s1[0], s1[1]), fmaxf(s1[2], s1[3])));
            vm = fmaxf(vm, __shfl_xor(vm, 16));
            vm = fmaxf(vm, __shfl_xor(vm, 32));
            if (!__all(vm <= mr + 8.f)) {        // rescale needed (rare later)
                const float mn = fmaxf(mr, vm);
                const float al = exp2f(mr - mn); // exp2(-inf)=0 on first tile
                mr = mn;
                lr *= al;
                float al4[4];
#pragma unroll
                for (int i = 0; i < 4; ++i) al4[i] = __shfl(al, 20 * g + i);
#pragma unroll
                for (int df = 0; df < 4; ++df) {
#pragma unroll
                    for (int i = 0; i < 4; ++i) acc[df][i] *= al4[i];
                }
            }
            float p0f[4], p1f[4];
#pragma unroll
            for (int i = 0; i < 4; ++i) {
                p0f[i] = exp2f(s0[i] - mr);      // masked -> exp2(-inf)=0
                p1f[i] = exp2f(s1[i] - mr);      // bounded by 2^8 when deferred
            }
            float rs = (p0f[0] + p0f[1]) + (p0f[2] + p0f[3])
                     + (p1f[0] + p1f[1]) + (p1f[2] + p1f[3]);
            rs += __shfl_xor(rs, 16);
            rs += __shfl_xor(rs, 32);
            lr += rs;
            // ---- P -> PV A-fragment, fully in-register ----
            u32 w0[4], w1[4];
#pragma unroll
            for (int i = 0; i < 4; ++i) {
                const float x0 = p0f[i];
                u32 b0; __builtin_memcpy(&b0, &x0, 4);
                u32 h0 = b0 & 0xffff0000u; float h0f; __builtin_memcpy(&h0f, &h0, 4);
                float l0f = x0 - h0f; u32 l0; __builtin_memcpy(&l0, &l0f, 4);
                w0[i] = (b0 >> 16) | (l0 & 0xffff0000u);
                const float x1 = p1f[i];
                u32 b1; __builtin_memcpy(&b1, &x1, 4);
                u32 h1 = b1 & 0xffff0000u; float h1f; __builtin_memcpy(&h1f, &h1, 4);
                float l1f = x1 - h1f; u32 l1; __builtin_memcpy(&l1, &l1f, 4);
                w1[i] = (b1 >> 16) | (l1 & 0xffff0000u);
            }
            const bool lowhalf = (lane < 32);    // g<2 -> keys<16 -> p0 array
            bf16x8 pa_h, pa_l;
#pragma unroll
            for (int i = 0; i < 4; ++i) {
                u32 t0a = (u32)__shfl((int)w0[i], srcA);
                u32 t1a = (u32)__shfl((int)w1[i], srcA);
                u32 t0b = (u32)__shfl((int)w0[i], srcB);
                u32 t1b = (u32)__shfl((int)w1[i], srcB);
                u32 ha = lowhalf ? t0a : t1a;
                u32 hb = lowhalf ? t0b : t1b;
                pa_h[i]     = (short)(ha & 0xffffu);
                pa_h[4 + i] = (short)(hb & 0xffffu);
                pa_l[i]     = (short)(ha >> 16);
                pa_l[4 + i] = (short)(hb >> 16);
            }
            // ---- PV: acc += P.V (split precision: PhVh + PhVl + PlVh) ----
            __builtin_amdgcn_s_setprio(1);
#pragma unroll
            for (int df = 0; df < 4; ++df) {
                const u16* vw = Vtc + (8 * df + (c >> 1)) * 128;
                bf16x8 vbh = *(const bf16x8*)(vw + sv);
                bf16x8 vbl = *(const bf16x8*)(vw + sv + 64);
                acc[df] = MFMA(pa_h, vbh, acc[df]);
                acc[df] = MFMA(pa_h, vbl, acc[df]);
                acc[df] = MFMA(pa_l, vbh, acc[df]);
            }
            __builtin_amdgcn_s_setprio(0);
        }
        __syncthreads();                     // end of trip: buf^1 now complete
    }

    // ---- epilogue: 1/l for query 4g+i lives at lane 20g+i ----
    float inv[4];
#pragma unroll
    for (int i = 0; i < 4; ++i) inv[i] = 1.f / __shfl(lr, 20 * g + i);
    if (IS_F32) {
        float* o = (float*)Ov + base;
#pragma unroll
        for (int df = 0; df < 4; ++df)
#pragma unroll
            for (int i = 0; i < 4; ++i)
                o[(size_t)(qb_w + 4 * g + i) * D_DIM + 16 * df + c] = acc[df][i] * inv[i];
    } else {
        __hip_bfloat16* o = (__hip_bfloat16*)Ov + base;
#pragma unroll
        for (int df = 0; df < 4; ++df)
#pragma unroll
            for (int i = 0; i < 4; ++i)
                o[(size_t)(qb_w + 4 * g + i) * D_DIM + 16 * df + c] =
                    __float2bfloat16(acc[df][i] * inv[i]);
    }
}

extern "C" void kernel_launch(void* const* d_in, const int* in_sizes, int n_in,
                              void* d_out, int out_size, void* d_ws, size_t ws_size,
                              hipStream_t stream) {
    const void* q  = d_in[0];
    const void* k  = d_in[1];
    const void* v  = d_in[2];
    const void* pq = d_in[3];
    const void* pk = d_in[4];
    // d_in[5] = causal mask, recomputed analytically in-kernel.
    int* flag = (int*)d_ws;

    detect_dtype_kernel<<<1, 64, 0, stream>>>((const u16*)q, flag);

    dim3 grid(NQT / 2, 32);                  // 16 pairs x 32 heads = 512 blocks
    attn_pair<false><<<grid, 512, 0, stream>>>(q, k, v, pq, pk, d_out, flag);
    attn_pair<true ><<<grid, 512, 0, stream>>>(q, k, v, pq, pk, d_out, flag);
}